// Round 11
// baseline (219.180 us; speedup 1.0000x reference)
//
#include <hip/hip_runtime.h>
#include <hip/hip_bf16.h>
#include <float.h>

#define LEAKY 0.2f
#define SCAN_B 512

__device__ __forceinline__ unsigned short f2bf_rne(float f) {
    unsigned u = __float_as_uint(f);
    unsigned r = (u + 0x7FFFu + ((u >> 16) & 1u)) >> 16;
    return (unsigned short)r;
}
__device__ __forceinline__ float bflo(unsigned u) { return __uint_as_float(u << 16); }
__device__ __forceinline__ float bfhi(unsigned u) { return __uint_as_float(u & 0xFFFF0000u); }

// ---------------- CSR build ----------------
__global__ void zero_k(int* __restrict__ p, int n) {
    int i = blockIdx.x * blockDim.x + threadIdx.x;
    if (i < n) p[i] = 0;
}

__global__ void rank_k(const int* __restrict__ dst, int* __restrict__ deg,
                       int* __restrict__ rank, int E) {
    int e = blockIdx.x * blockDim.x + threadIdx.x;
    if (e < E) rank[e] = atomicAdd(&deg[dst[e]], 1);
}

__global__ void scan1_k(const int* __restrict__ deg, int* __restrict__ offs,
                        int* __restrict__ bsum, int N) {
    __shared__ int s[SCAN_B];
    int i = blockIdx.x * SCAN_B + threadIdx.x;
    int v = (i < N) ? deg[i] : 0;
    s[threadIdx.x] = v;
    __syncthreads();
    for (int off = 1; off < SCAN_B; off <<= 1) {
        int t = (threadIdx.x >= off) ? s[threadIdx.x - off] : 0;
        __syncthreads();
        s[threadIdx.x] += t;
        __syncthreads();
    }
    if (i < N) offs[i] = s[threadIdx.x] - v;   // exclusive
    if (threadIdx.x == SCAN_B - 1) bsum[blockIdx.x] = s[threadIdx.x];
}

__global__ void scan2_k(int* __restrict__ bsum, int* __restrict__ offs, int NB, int N) {
    int lane = threadIdx.x;   // 64 threads
    int carry = 0;
    for (int base = 0; base < NB; base += 64) {
        int i = base + lane;
        int v = (i < NB) ? bsum[i] : 0;
        int s = v;
        for (int o = 1; o < 64; o <<= 1) {
            int t = __shfl_up(s, o, 64);
            if (lane >= o) s += t;
        }
        if (i < NB) bsum[i] = s - v + carry;
        carry += __shfl(s, 63, 64);
    }
    if (lane == 0) offs[N] = carry;
}

__global__ void scan3_k(int* __restrict__ offs, const int* __restrict__ bsum, int N) {
    int i = blockIdx.x * blockDim.x + threadIdx.x;
    if (i < N) offs[i] += bsum[i / SCAN_B];
}

__global__ void scatter_k(const int* __restrict__ src, const int* __restrict__ dst,
                          const int* __restrict__ et, const int* __restrict__ offs,
                          const int* __restrict__ rank, unsigned* __restrict__ pedge, int E) {
    int e = blockIdx.x * blockDim.x + threadIdx.x;
    if (e < E) {
        int j = offs[dst[e]] + rank[e];
        pedge[j] = ((unsigned)et[e] << 28) | (unsigned)src[e];
    }
}

// ---------------- layer-0 GEMM + logits ----------------
template <int FIN>
__global__ __launch_bounds__(256) void gemm_fused_k(const float* __restrict__ in,
                                                    const float* __restrict__ W,
                                                    const float* __restrict__ a_s,
                                                    const float* __restrict__ a_d,
                                                    unsigned short* __restrict__ h,
                                                    float* __restrict__ ls,
                                                    float* __restrict__ ld_, int N) {
    __shared__ float in_s[64][FIN + 4];
    __shared__ float Wl[FIN][64];

    const int rbase = blockIdx.x * 64;
    const int NV4 = FIN / 4;

    for (int t = threadIdx.x; t < FIN * 16; t += 256) {
        float4 v = *(const float4*)(W + (size_t)t * 4);
        *(float4*)((float*)Wl + (size_t)t * 4) = v;
    }
    for (int t = threadIdx.x; t < 64 * NV4; t += 256) {
        int r = t / NV4, k4 = t % NV4;
        int gr = rbase + r;
        if (gr >= N) gr = N - 1;
        float4 v = *(const float4*)(in + (size_t)gr * FIN + k4 * 4);
        *(float4*)&in_s[r][k4 * 4] = v;
    }
    __syncthreads();

    const int ty = threadIdx.x >> 4;
    const int tx = threadIdx.x & 15;

    float acc[4][4] = {};
#pragma unroll 4
    for (int k = 0; k < FIN; ++k) {
        float4 wv = *(const float4*)&Wl[k][tx * 4];
        float a0 = in_s[ty * 4 + 0][k];
        float a1 = in_s[ty * 4 + 1][k];
        float a2 = in_s[ty * 4 + 2][k];
        float a3 = in_s[ty * 4 + 3][k];
        acc[0][0] += a0 * wv.x; acc[0][1] += a0 * wv.y; acc[0][2] += a0 * wv.z; acc[0][3] += a0 * wv.w;
        acc[1][0] += a1 * wv.x; acc[1][1] += a1 * wv.y; acc[1][2] += a1 * wv.z; acc[1][3] += a1 * wv.w;
        acc[2][0] += a2 * wv.x; acc[2][1] += a2 * wv.y; acc[2][2] += a2 * wv.z; acc[2][3] += a2 * wv.w;
        acc[3][0] += a3 * wv.x; acc[3][1] += a3 * wv.y; acc[3][2] += a3 * wv.z; acc[3][3] += a3 * wv.w;
    }

    float4 asv = *(const float4*)(a_s + tx * 4);
    float4 adv = *(const float4*)(a_d + tx * 4);
#pragma unroll
    for (int i = 0; i < 4; ++i) {
        int row = rbase + ty * 4 + i;
        float lsv = acc[i][0] * asv.x + acc[i][1] * asv.y + acc[i][2] * asv.z + acc[i][3] * asv.w;
        float ldv = acc[i][0] * adv.x + acc[i][1] * adv.y + acc[i][2] * adv.z + acc[i][3] * adv.w;
        for (int o = 1; o < 16; o <<= 1) {
            lsv += __shfl_xor(lsv, o, 64);
            ldv += __shfl_xor(ldv, o, 64);
        }
        if (row < N) {
            ushort4 hv;
            hv.x = f2bf_rne(acc[i][0]);
            hv.y = f2bf_rne(acc[i][1]);
            hv.z = f2bf_rne(acc[i][2]);
            hv.w = f2bf_rne(acc[i][3]);
            ((ushort4*)h)[(size_t)row * 16 + tx] = hv;
            if (tx == 0) { ls[row] = lsv; ld_[row] = ldv; }
        }
    }
}

// etb select: registers + cndmask (T<=4)
__device__ __forceinline__ float etb_sel(const float4& eb, const float* __restrict__ etb,
                                         int T, unsigned t) {
    if (T <= 4) return t == 0 ? eb.x : (t == 1 ? eb.y : (t == 2 ? eb.z : eb.w));
    return etb[t];
}

// 8-edge unrolled accumulation step (static indexing keeps arrays in VGPRs)
#define EDGE_BLOCK(CNT)                                                              \
    {                                                                                \
        unsigned pp[CNT]; unsigned nn[CNT]; uint4 vv[CNT]; float w[CNT];             \
        _Pragma("unroll")                                                            \
        for (int q = 0; q < CNT; ++q) pp[q] = pedge[j + q];                          \
        _Pragma("unroll")                                                            \
        for (int q = 0; q < CNT; ++q) nn[q] = pp[q] & 0x0FFFFFFFu;                   \
        _Pragma("unroll")                                                            \
        for (int q = 0; q < CNT; ++q) vv[q] = h4[(size_t)nn[q] * 8 + l];             \
        _Pragma("unroll")                                                            \
        for (int q = 0; q < CNT; ++q) {                                              \
            float e = ls_in[nn[q]] + myld + etb_sel(eb, etb, T, pp[q] >> 28);        \
            e = e > 0.f ? e : LEAKY * e;                                             \
            w[q] = __expf(e);                                                        \
            aw_ += w[q];                                                             \
        }                                                                            \
        _Pragma("unroll")                                                            \
        for (int q = 0; q < CNT; ++q) {                                              \
            acc[0] += bflo(vv[q].x) * w[q]; acc[1] += bfhi(vv[q].x) * w[q];          \
            acc[2] += bflo(vv[q].y) * w[q]; acc[3] += bfhi(vv[q].y) * w[q];          \
            acc[4] += bflo(vv[q].z) * w[q]; acc[5] += bfhi(vv[q].z) * w[q];          \
            acc[6] += bflo(vv[q].w) * w[q]; acc[7] += bfhi(vv[q].w) * w[q];          \
        }                                                                            \
    }

// ---------------- fused attn (single-pass, 8-unroll) + GEMM + logits ----------------
// LDS holds only act (17.4 KB) -> 8 blocks/CU; W read via L1 in gemm phase.
__global__ __launch_bounds__(256) void attn_gemm_k(const int* __restrict__ offs,
                                                   const unsigned* __restrict__ pedge,
                                                   const float* __restrict__ ls_in,
                                                   const float* __restrict__ ld_in,
                                                   const float* __restrict__ etb, int T,
                                                   const unsigned short* __restrict__ h_in,
                                                   const float* __restrict__ W,
                                                   const float* __restrict__ a_s,
                                                   const float* __restrict__ a_d,
                                                   unsigned short* __restrict__ h_out,
                                                   float* __restrict__ ls_out,
                                                   float* __restrict__ ld_out, int N) {
    __shared__ float act[64][68];

    const int rbase = blockIdx.x * 64;

    float4 eb;
    eb.x = etb[0];
    eb.y = T > 1 ? etb[1] : etb[0];
    eb.z = T > 2 ? etb[2] : etb[0];
    eb.w = T > 3 ? etb[3] : etb[0];

    const int grp = threadIdx.x >> 3;
    const int l = threadIdx.x & 7;
    const uint4* h4 = (const uint4*)h_in;

    for (int p = 0; p < 2; ++p) {
        int r = p * 32 + grp;
        int n = rbase + r;
        float acc[8] = {};
        float aw_ = 0.f;
        if (n < N) {
            int s0 = offs[n], s1 = offs[n + 1];
            float myld = ld_in[n];
            int j = s0;
            for (; j + 7 < s1; j += 8) EDGE_BLOCK(8)
            if (j + 3 < s1) { EDGE_BLOCK(4) j += 4; }
            for (; j < s1; j++) EDGE_BLOCK(1)
        }
        float invd = 1.0f / (aw_ + 1e-16f);
        float4 o0, o1;
        o0.x = fmaxf(acc[0] * invd, 0.f); o0.y = fmaxf(acc[1] * invd, 0.f);
        o0.z = fmaxf(acc[2] * invd, 0.f); o0.w = fmaxf(acc[3] * invd, 0.f);
        o1.x = fmaxf(acc[4] * invd, 0.f); o1.y = fmaxf(acc[5] * invd, 0.f);
        o1.z = fmaxf(acc[6] * invd, 0.f); o1.w = fmaxf(acc[7] * invd, 0.f);
        if (n >= N) { o0 = make_float4(0, 0, 0, 0); o1 = o0; }
        *(float4*)&act[r][l * 8] = o0;
        *(float4*)&act[r][l * 8 + 4] = o1;
    }
    __syncthreads();

    // ---- gemm phase: act (LDS) x W (global, L1-broadcast) ----
    const int ty = threadIdx.x >> 4;
    const int tx = threadIdx.x & 15;

    float acc[4][4] = {};
#pragma unroll 4
    for (int k = 0; k < 64; ++k) {
        float4 wv = *(const float4*)(W + (size_t)k * 64 + tx * 4);
        float a0 = act[ty * 4 + 0][k];
        float a1 = act[ty * 4 + 1][k];
        float a2 = act[ty * 4 + 2][k];
        float a3 = act[ty * 4 + 3][k];
        acc[0][0] += a0 * wv.x; acc[0][1] += a0 * wv.y; acc[0][2] += a0 * wv.z; acc[0][3] += a0 * wv.w;
        acc[1][0] += a1 * wv.x; acc[1][1] += a1 * wv.y; acc[1][2] += a1 * wv.z; acc[1][3] += a1 * wv.w;
        acc[2][0] += a2 * wv.x; acc[2][1] += a2 * wv.y; acc[2][2] += a2 * wv.z; acc[2][3] += a2 * wv.w;
        acc[3][0] += a3 * wv.x; acc[3][1] += a3 * wv.y; acc[3][2] += a3 * wv.z; acc[3][3] += a3 * wv.w;
    }

    float4 asv = *(const float4*)(a_s + tx * 4);
    float4 adv = *(const float4*)(a_d + tx * 4);
#pragma unroll
    for (int i = 0; i < 4; ++i) {
        int row = rbase + ty * 4 + i;
        float lsv = acc[i][0] * asv.x + acc[i][1] * asv.y + acc[i][2] * asv.z + acc[i][3] * asv.w;
        float ldv = acc[i][0] * adv.x + acc[i][1] * adv.y + acc[i][2] * adv.z + acc[i][3] * adv.w;
        for (int o = 1; o < 16; o <<= 1) {
            lsv += __shfl_xor(lsv, o, 64);
            ldv += __shfl_xor(ldv, o, 64);
        }
        if (row < N) {
            ushort4 hv;
            hv.x = f2bf_rne(acc[i][0]);
            hv.y = f2bf_rne(acc[i][1]);
            hv.z = f2bf_rne(acc[i][2]);
            hv.w = f2bf_rne(acc[i][3]);
            ((ushort4*)h_out)[(size_t)row * 16 + tx] = hv;
            if (tx == 0) { ls_out[row] = lsv; ld_out[row] = ldv; }
        }
    }
}

// ---------------- final attn (single-pass, 8-unroll, fp32 output) ----------------
__global__ __launch_bounds__(256) void attn_final_k(const int* __restrict__ offs,
                                                    const unsigned* __restrict__ pedge,
                                                    const float* __restrict__ ls_in,
                                                    const float* __restrict__ ld_in,
                                                    const float* __restrict__ etb, int T,
                                                    const unsigned short* __restrict__ h_in,
                                                    float* __restrict__ out, int N) {
    const int grp = threadIdx.x >> 3;
    const int l = threadIdx.x & 7;
    int n = blockIdx.x * 32 + grp;
    if (n >= N) return;
    int s0 = offs[n], s1 = offs[n + 1];
    float myld = ld_in[n];
    const uint4* h4 = (const uint4*)h_in;

    float4 eb;
    eb.x = etb[0];
    eb.y = T > 1 ? etb[1] : etb[0];
    eb.z = T > 2 ? etb[2] : etb[0];
    eb.w = T > 3 ? etb[3] : etb[0];

    float acc[8] = {};
    float aw_ = 0.f;
    int j = s0;
    for (; j + 7 < s1; j += 8) EDGE_BLOCK(8)
    if (j + 3 < s1) { EDGE_BLOCK(4) j += 4; }
    for (; j < s1; j++) EDGE_BLOCK(1)

    float invd = 1.0f / (aw_ + 1e-16f);
    float4 o0, o1;
    o0.x = fmaxf(acc[0] * invd, 0.f); o0.y = fmaxf(acc[1] * invd, 0.f);
    o0.z = fmaxf(acc[2] * invd, 0.f); o0.w = fmaxf(acc[3] * invd, 0.f);
    o1.x = fmaxf(acc[4] * invd, 0.f); o1.y = fmaxf(acc[5] * invd, 0.f);
    o1.z = fmaxf(acc[6] * invd, 0.f); o1.w = fmaxf(acc[7] * invd, 0.f);
    *(float4*)&out[(size_t)n * 64 + l * 8] = o0;
    *(float4*)&out[(size_t)n * 64 + l * 8 + 4] = o1;
}

// ---------------- fused pool + critic MLP ----------------
__global__ __launch_bounds__(128) void poolmlp_k(const int* __restrict__ batch,
                                                 const float* __restrict__ act,
                                                 const float* __restrict__ W0,
                                                 const float* __restrict__ b0,
                                                 const float* __restrict__ W1,
                                                 const float* __restrict__ b1,
                                                 const float* __restrict__ fW,
                                                 const float* __restrict__ fb,
                                                 float* __restrict__ out, int N) {
    __shared__ float s[128];
    __shared__ float gv[64];
    __shared__ float t1[128];
    __shared__ float t2[128];
    __shared__ float part[2];
    int g = blockIdx.x;
    int t = threadIdx.x;
    int f = t & 63;
    int rc = t >> 6;   // 0..1
    int lo, hi;
    { int a = 0, b = N; while (a < b) { int m = (a + b) >> 1; if (batch[m] < g) a = m + 1; else b = m; } lo = a; }
    { int a = lo, b = N; while (a < b) { int m = (a + b) >> 1; if (batch[m] < g + 1) a = m + 1; else b = m; } hi = a; }
    float acc = 0.f;
    for (int n = lo + rc; n < hi; n += 2) acc += act[(size_t)n * 64 + f];
    s[t] = acc;
    __syncthreads();
    if (t < 64) gv[t] = s[t] + s[t + 64];
    __syncthreads();
    acc = b0[t];
    for (int k = 0; k < 64; k++) acc += gv[k] * W0[k * 128 + t];
    t1[t] = fmaxf(acc, 0.f);
    __syncthreads();
    acc = b1[t];
    for (int k = 0; k < 128; k++) acc += t1[k] * W1[k * 128 + t];
    t2[t] = fmaxf(acc, 0.f);
    __syncthreads();
    float v = t2[t] * fW[t];
    for (int o = 32; o > 0; o >>= 1) v += __shfl_xor(v, o, 64);
    if ((t & 63) == 0) part[t >> 6] = v;
    __syncthreads();
    if (t == 0) out[g] = part[0] + part[1] + fb[0];
}

extern "C" void kernel_launch(void* const* d_in, const int* in_sizes, int n_in,
                              void* d_out, int out_size, void* d_ws, size_t ws_size,
                              hipStream_t stream) {
    const float* x    = (const float*)d_in[0];
    const int*   src  = (const int*)d_in[1];
    const int*   dst  = (const int*)d_in[2];
    const int*   et   = (const int*)d_in[3];
    const int*   batch= (const int*)d_in[4];
    const float* W0   = (const float*)d_in[6];
    const float* W1   = (const float*)d_in[7];
    const float* W2   = (const float*)d_in[8];
    const float* a_src= (const float*)d_in[9];
    const float* a_dst= (const float*)d_in[10];
    const float* etb  = (const float*)d_in[11];
    const float* eW0  = (const float*)d_in[12];
    const float* eb0  = (const float*)d_in[13];
    const float* eW1  = (const float*)d_in[14];
    const float* eb1  = (const float*)d_in[15];
    const float* fW   = (const float*)d_in[16];
    const float* fb   = (const float*)d_in[17];
    float* out = (float*)d_out;

    const int H = in_sizes[9] / 3;       // 64
    const int F = in_sizes[6] / H;       // 128
    const int N = in_sizes[0] / F;       // 50000
    const int E = in_sizes[1];           // 800000
    const int T = in_sizes[11] / 3;      // 3
    const int G = out_size;              // 512

    unsigned short* hA = (unsigned short*)d_ws;                 // N*64 bf16
    unsigned short* hC = hA + (size_t)N * 64;                   // N*64 bf16
    float*    hB    = (float*)(hC + (size_t)N * 64);            // N*64 fp32
    float*    ls0   = hB + (size_t)N * 64;                      // N
    float*    ld0   = ls0 + N;                                  // N
    float*    ls1   = ld0 + N;                                  // N
    float*    ld1   = ls1 + N;                                  // N
    int*      deg   = (int*)(ld1 + N);                          // N
    int*      offs  = deg + N;                                  // N+1
    int*      rank  = offs + N + 1;                             // E
    unsigned* pedge = (unsigned*)(rank + E);                    // E
    int*      bsum  = (int*)(pedge + E);                        // NB

    const int NB = (N + SCAN_B - 1) / SCAN_B;
    const int NB64 = (N + 63) / 64;
    const int NB32 = (N + 31) / 32;

    zero_k<<<(N + 255) / 256, 256, 0, stream>>>(deg, N);
    rank_k<<<(E + 255) / 256, 256, 0, stream>>>(dst, deg, rank, E);
    scan1_k<<<NB, SCAN_B, 0, stream>>>(deg, offs, bsum, N);
    scan2_k<<<1, 64, 0, stream>>>(bsum, offs, NB, N);
    scan3_k<<<NB, SCAN_B, 0, stream>>>(offs, bsum, N);
    scatter_k<<<(E + 255) / 256, 256, 0, stream>>>(src, dst, et, offs, rank, pedge, E);

    // layer 0: x -> h0 (hA), logits0
    gemm_fused_k<128><<<NB64, 256, 0, stream>>>(x, W0, a_src + 0 * H, a_dst + 0 * H, hA, ls0, ld0, N);
    // layer 1: attn(h0) -> gemm W1 -> h1 (hC), logits1
    attn_gemm_k<<<NB64, 256, 0, stream>>>(offs, pedge, ls0, ld0, etb + 0 * T, T, hA,
                                          W1, a_src + 1 * H, a_dst + 1 * H, hC, ls1, ld1, N);
    // layer 2: attn(h1) -> gemm W2 -> h2 (hA), logits2
    attn_gemm_k<<<NB64, 256, 0, stream>>>(offs, pedge, ls1, ld1, etb + 1 * T, T, hC,
                                          W2, a_src + 2 * H, a_dst + 2 * H, hA, ls0, ld0, N);
    // final attn: attn(h2) -> hB (fp32)
    attn_final_k<<<NB32, 256, 0, stream>>>(offs, pedge, ls0, ld0, etb + 2 * T, T, hA, hB, N);

    // pool + MLP
    poolmlp_k<<<G, 128, 0, stream>>>(batch, hB, eW0, eb0, eW1, eb1, fW, fb, out, N);
}

// Round 12
// 195.813 us; speedup vs baseline: 1.1193x; 1.1193x over previous
//
#include <hip/hip_runtime.h>
#include <hip/hip_bf16.h>
#include <float.h>

#define LEAKY 0.2f
#define SCAN_B 512

__device__ __forceinline__ unsigned short f2bf_rne(float f) {
    unsigned u = __float_as_uint(f);
    unsigned r = (u + 0x7FFFu + ((u >> 16) & 1u)) >> 16;
    return (unsigned short)r;
}
__device__ __forceinline__ float bflo(unsigned u) { return __uint_as_float(u << 16); }
__device__ __forceinline__ float bfhi(unsigned u) { return __uint_as_float(u & 0xFFFF0000u); }

// ---------------- CSR build ----------------
__global__ void zero_k(int* __restrict__ p, int n) {
    int i = blockIdx.x * blockDim.x + threadIdx.x;
    if (i < n) p[i] = 0;
}

__global__ void rank_k(const int* __restrict__ dst, int* __restrict__ deg,
                       int* __restrict__ rank, int E) {
    int e = blockIdx.x * blockDim.x + threadIdx.x;
    if (e < E) rank[e] = atomicAdd(&deg[dst[e]], 1);
}

__global__ void scan1_k(const int* __restrict__ deg, int* __restrict__ offs,
                        int* __restrict__ bsum, int N) {
    __shared__ int s[SCAN_B];
    int i = blockIdx.x * SCAN_B + threadIdx.x;
    int v = (i < N) ? deg[i] : 0;
    s[threadIdx.x] = v;
    __syncthreads();
    for (int off = 1; off < SCAN_B; off <<= 1) {
        int t = (threadIdx.x >= off) ? s[threadIdx.x - off] : 0;
        __syncthreads();
        s[threadIdx.x] += t;
        __syncthreads();
    }
    if (i < N) offs[i] = s[threadIdx.x] - v;   // exclusive
    if (threadIdx.x == SCAN_B - 1) bsum[blockIdx.x] = s[threadIdx.x];
}

__global__ void scan2_k(int* __restrict__ bsum, int* __restrict__ offs, int NB, int N) {
    int lane = threadIdx.x;   // 64 threads
    int carry = 0;
    for (int base = 0; base < NB; base += 64) {
        int i = base + lane;
        int v = (i < NB) ? bsum[i] : 0;
        int s = v;
        for (int o = 1; o < 64; o <<= 1) {
            int t = __shfl_up(s, o, 64);
            if (lane >= o) s += t;
        }
        if (i < NB) bsum[i] = s - v + carry;
        carry += __shfl(s, 63, 64);
    }
    if (lane == 0) offs[N] = carry;
}

__global__ void scan3_k(int* __restrict__ offs, const int* __restrict__ bsum, int N) {
    int i = blockIdx.x * blockDim.x + threadIdx.x;
    if (i < N) offs[i] += bsum[i / SCAN_B];
}

__global__ void scatter_k(const int* __restrict__ src, const int* __restrict__ dst,
                          const int* __restrict__ et, const int* __restrict__ offs,
                          const int* __restrict__ rank, unsigned* __restrict__ pedge, int E) {
    int e = blockIdx.x * blockDim.x + threadIdx.x;
    if (e < E) {
        int j = offs[dst[e]] + rank[e];
        pedge[j] = ((unsigned)et[e] << 28) | (unsigned)src[e];
    }
}

// ---------------- layer-0 GEMM + logits ----------------
template <int FIN>
__global__ __launch_bounds__(256) void gemm_fused_k(const float* __restrict__ in,
                                                    const float* __restrict__ W,
                                                    const float* __restrict__ a_s,
                                                    const float* __restrict__ a_d,
                                                    unsigned short* __restrict__ h,
                                                    float* __restrict__ ls,
                                                    float* __restrict__ ld_, int N) {
    __shared__ float in_s[64][FIN + 4];
    __shared__ float Wl[FIN][64];

    const int rbase = blockIdx.x * 64;
    const int NV4 = FIN / 4;

    for (int t = threadIdx.x; t < FIN * 16; t += 256) {
        float4 v = *(const float4*)(W + (size_t)t * 4);
        *(float4*)((float*)Wl + (size_t)t * 4) = v;
    }
    for (int t = threadIdx.x; t < 64 * NV4; t += 256) {
        int r = t / NV4, k4 = t % NV4;
        int gr = rbase + r;
        if (gr >= N) gr = N - 1;
        float4 v = *(const float4*)(in + (size_t)gr * FIN + k4 * 4);
        *(float4*)&in_s[r][k4 * 4] = v;
    }
    __syncthreads();

    const int ty = threadIdx.x >> 4;
    const int tx = threadIdx.x & 15;

    float acc[4][4] = {};
#pragma unroll 4
    for (int k = 0; k < FIN; ++k) {
        float4 wv = *(const float4*)&Wl[k][tx * 4];
        float a0 = in_s[ty * 4 + 0][k];
        float a1 = in_s[ty * 4 + 1][k];
        float a2 = in_s[ty * 4 + 2][k];
        float a3 = in_s[ty * 4 + 3][k];
        acc[0][0] += a0 * wv.x; acc[0][1] += a0 * wv.y; acc[0][2] += a0 * wv.z; acc[0][3] += a0 * wv.w;
        acc[1][0] += a1 * wv.x; acc[1][1] += a1 * wv.y; acc[1][2] += a1 * wv.z; acc[1][3] += a1 * wv.w;
        acc[2][0] += a2 * wv.x; acc[2][1] += a2 * wv.y; acc[2][2] += a2 * wv.z; acc[2][3] += a2 * wv.w;
        acc[3][0] += a3 * wv.x; acc[3][1] += a3 * wv.y; acc[3][2] += a3 * wv.z; acc[3][3] += a3 * wv.w;
    }

    float4 asv = *(const float4*)(a_s + tx * 4);
    float4 adv = *(const float4*)(a_d + tx * 4);
#pragma unroll
    for (int i = 0; i < 4; ++i) {
        int row = rbase + ty * 4 + i;
        float lsv = acc[i][0] * asv.x + acc[i][1] * asv.y + acc[i][2] * asv.z + acc[i][3] * asv.w;
        float ldv = acc[i][0] * adv.x + acc[i][1] * adv.y + acc[i][2] * adv.z + acc[i][3] * adv.w;
        for (int o = 1; o < 16; o <<= 1) {
            lsv += __shfl_xor(lsv, o, 64);
            ldv += __shfl_xor(ldv, o, 64);
        }
        if (row < N) {
            ushort4 hv;
            hv.x = f2bf_rne(acc[i][0]);
            hv.y = f2bf_rne(acc[i][1]);
            hv.z = f2bf_rne(acc[i][2]);
            hv.w = f2bf_rne(acc[i][3]);
            ((ushort4*)h)[(size_t)row * 16 + tx] = hv;
            if (tx == 0) { ls[row] = lsv; ld_[row] = ldv; }
        }
    }
}

// ---------------- fused attn (two-pass, R7 structure) + GEMM, 32 nodes/block ----------------
__global__ __launch_bounds__(256) void attn_gemm_k(const int* __restrict__ offs,
                                                   const unsigned* __restrict__ pedge,
                                                   const float* __restrict__ ls_in,
                                                   const float* __restrict__ ld_in,
                                                   const float* __restrict__ etb,
                                                   const unsigned short* __restrict__ h_in,
                                                   const float* __restrict__ W,
                                                   const float* __restrict__ a_s,
                                                   const float* __restrict__ a_d,
                                                   unsigned short* __restrict__ h_out,
                                                   float* __restrict__ ls_out,
                                                   float* __restrict__ ld_out, int N) {
    __shared__ float Wl[64][64];
    __shared__ float act[32][68];

    const int rbase = blockIdx.x * 32;

    for (int t = threadIdx.x; t < 64 * 16; t += 256)
        *(float4*)((float*)Wl + (size_t)t * 4) = *(const float4*)(W + (size_t)t * 4);

    const int grp = threadIdx.x >> 3;   // 0..31 -> one node per group
    const int l = threadIdx.x & 7;
    const uint4* h4 = (const uint4*)h_in;

    {
        int n = rbase + grp;
        float acc[8] = {};
        float aw_ = 0.f;
        if (n < N) {
            int s0 = offs[n], s1 = offs[n + 1];
            float myld = ld_in[n];
            // pass 1: lane-parallel max (also warms pedge/ls in cache)
            float mx = -FLT_MAX;
            for (int j = s0 + l; j < s1; j += 8) {
                unsigned pp = pedge[j];
                float ev = ls_in[pp & 0x0FFFFFFFu] + myld + etb[pp >> 28];
                ev = ev > 0.f ? ev : LEAKY * ev;
                mx = fmaxf(mx, ev);
            }
#pragma unroll
            for (int o = 1; o < 8; o <<= 1) mx = fmaxf(mx, __shfl_xor(mx, o, 64));

            // pass 2: group-serial 4-unroll accumulate
            int j = s0;
            for (; j + 3 < s1; j += 4) {
                unsigned p0 = pedge[j], p1 = pedge[j + 1], p2 = pedge[j + 2], p3 = pedge[j + 3];
                unsigned n0 = p0 & 0x0FFFFFFFu, n1 = p1 & 0x0FFFFFFFu;
                unsigned n2 = p2 & 0x0FFFFFFFu, n3 = p3 & 0x0FFFFFFFu;
                float e0 = ls_in[n0] + myld + etb[p0 >> 28]; e0 = e0 > 0.f ? e0 : LEAKY * e0;
                float e1 = ls_in[n1] + myld + etb[p1 >> 28]; e1 = e1 > 0.f ? e1 : LEAKY * e1;
                float e2 = ls_in[n2] + myld + etb[p2 >> 28]; e2 = e2 > 0.f ? e2 : LEAKY * e2;
                float e3 = ls_in[n3] + myld + etb[p3 >> 28]; e3 = e3 > 0.f ? e3 : LEAKY * e3;
                float w0 = __expf(e0 - mx), w1 = __expf(e1 - mx);
                float w2 = __expf(e2 - mx), w3 = __expf(e3 - mx);
                uint4 v0 = h4[(size_t)n0 * 8 + l];
                uint4 v1 = h4[(size_t)n1 * 8 + l];
                uint4 v2 = h4[(size_t)n2 * 8 + l];
                uint4 v3 = h4[(size_t)n3 * 8 + l];
                aw_ += (w0 + w1) + (w2 + w3);
                acc[0] += bflo(v0.x) * w0 + bflo(v1.x) * w1 + bflo(v2.x) * w2 + bflo(v3.x) * w3;
                acc[1] += bfhi(v0.x) * w0 + bfhi(v1.x) * w1 + bfhi(v2.x) * w2 + bfhi(v3.x) * w3;
                acc[2] += bflo(v0.y) * w0 + bflo(v1.y) * w1 + bflo(v2.y) * w2 + bflo(v3.y) * w3;
                acc[3] += bfhi(v0.y) * w0 + bfhi(v1.y) * w1 + bfhi(v2.y) * w2 + bfhi(v3.y) * w3;
                acc[4] += bflo(v0.z) * w0 + bflo(v1.z) * w1 + bflo(v2.z) * w2 + bflo(v3.z) * w3;
                acc[5] += bfhi(v0.z) * w0 + bfhi(v1.z) * w1 + bfhi(v2.z) * w2 + bfhi(v3.z) * w3;
                acc[6] += bflo(v0.w) * w0 + bflo(v1.w) * w1 + bflo(v2.w) * w2 + bflo(v3.w) * w3;
                acc[7] += bfhi(v0.w) * w0 + bfhi(v1.w) * w1 + bfhi(v2.w) * w2 + bfhi(v3.w) * w3;
            }
            for (; j < s1; j++) {
                unsigned p0 = pedge[j];
                unsigned n0 = p0 & 0x0FFFFFFFu;
                float e0 = ls_in[n0] + myld + etb[p0 >> 28]; e0 = e0 > 0.f ? e0 : LEAKY * e0;
                float w0 = __expf(e0 - mx);
                uint4 v0 = h4[(size_t)n0 * 8 + l];
                aw_ += w0;
                acc[0] += bflo(v0.x) * w0; acc[1] += bfhi(v0.x) * w0;
                acc[2] += bflo(v0.y) * w0; acc[3] += bfhi(v0.y) * w0;
                acc[4] += bflo(v0.z) * w0; acc[5] += bfhi(v0.z) * w0;
                acc[6] += bflo(v0.w) * w0; acc[7] += bfhi(v0.w) * w0;
            }
        }
        float invd = 1.0f / (aw_ + 1e-16f);
        float4 o0, o1;
        o0.x = fmaxf(acc[0] * invd, 0.f); o0.y = fmaxf(acc[1] * invd, 0.f);
        o0.z = fmaxf(acc[2] * invd, 0.f); o0.w = fmaxf(acc[3] * invd, 0.f);
        o1.x = fmaxf(acc[4] * invd, 0.f); o1.y = fmaxf(acc[5] * invd, 0.f);
        o1.z = fmaxf(acc[6] * invd, 0.f); o1.w = fmaxf(acc[7] * invd, 0.f);
        if (rbase + grp >= N) { o0 = make_float4(0, 0, 0, 0); o1 = o0; }
        *(float4*)&act[grp][l * 8] = o0;
        *(float4*)&act[grp][l * 8 + 4] = o1;
    }
    __syncthreads();

    // ---- gemm phase: 32 rows x 64 cols; each thread 2 rows x 4 cols ----
    const int ty = threadIdx.x >> 4;   // 0..15 -> 2 rows each
    const int tx = threadIdx.x & 15;

    float acc[2][4] = {};
#pragma unroll 4
    for (int k = 0; k < 64; ++k) {
        float4 wv = *(const float4*)&Wl[k][tx * 4];
        float a0 = act[ty * 2 + 0][k];
        float a1 = act[ty * 2 + 1][k];
        acc[0][0] += a0 * wv.x; acc[0][1] += a0 * wv.y; acc[0][2] += a0 * wv.z; acc[0][3] += a0 * wv.w;
        acc[1][0] += a1 * wv.x; acc[1][1] += a1 * wv.y; acc[1][2] += a1 * wv.z; acc[1][3] += a1 * wv.w;
    }

    float4 asv = *(const float4*)(a_s + tx * 4);
    float4 adv = *(const float4*)(a_d + tx * 4);
#pragma unroll
    for (int i = 0; i < 2; ++i) {
        int row = rbase + ty * 2 + i;
        float lsv = acc[i][0] * asv.x + acc[i][1] * asv.y + acc[i][2] * asv.z + acc[i][3] * asv.w;
        float ldv = acc[i][0] * adv.x + acc[i][1] * adv.y + acc[i][2] * adv.z + acc[i][3] * adv.w;
        for (int o = 1; o < 16; o <<= 1) {
            lsv += __shfl_xor(lsv, o, 64);
            ldv += __shfl_xor(ldv, o, 64);
        }
        if (row < N) {
            ushort4 hv;
            hv.x = f2bf_rne(acc[i][0]);
            hv.y = f2bf_rne(acc[i][1]);
            hv.z = f2bf_rne(acc[i][2]);
            hv.w = f2bf_rne(acc[i][3]);
            ((ushort4*)h_out)[(size_t)row * 16 + tx] = hv;
            if (tx == 0) { ls_out[row] = lsv; ld_out[row] = ldv; }
        }
    }
}

// ---------------- final attn (two-pass, R7 structure, fp32 output) ----------------
__global__ __launch_bounds__(256) void attn_final_k(const int* __restrict__ offs,
                                                    const unsigned* __restrict__ pedge,
                                                    const float* __restrict__ ls_in,
                                                    const float* __restrict__ ld_in,
                                                    const float* __restrict__ etb,
                                                    const unsigned short* __restrict__ h_in,
                                                    float* __restrict__ out, int N) {
    const int grp = threadIdx.x >> 3;
    const int l = threadIdx.x & 7;
    int n = blockIdx.x * 32 + grp;
    if (n >= N) return;
    int s0 = offs[n], s1 = offs[n + 1];
    float myld = ld_in[n];
    const uint4* h4 = (const uint4*)h_in;

    float mx = -FLT_MAX;
    for (int j = s0 + l; j < s1; j += 8) {
        unsigned pp = pedge[j];
        float ev = ls_in[pp & 0x0FFFFFFFu] + myld + etb[pp >> 28];
        ev = ev > 0.f ? ev : LEAKY * ev;
        mx = fmaxf(mx, ev);
    }
#pragma unroll
    for (int o = 1; o < 8; o <<= 1) mx = fmaxf(mx, __shfl_xor(mx, o, 64));

    float acc[8] = {};
    float aw_ = 0.f;
    int j = s0;
    for (; j + 3 < s1; j += 4) {
        unsigned p0 = pedge[j], p1 = pedge[j + 1], p2 = pedge[j + 2], p3 = pedge[j + 3];
        unsigned n0 = p0 & 0x0FFFFFFFu, n1 = p1 & 0x0FFFFFFFu;
        unsigned n2 = p2 & 0x0FFFFFFFu, n3 = p3 & 0x0FFFFFFFu;
        float e0 = ls_in[n0] + myld + etb[p0 >> 28]; e0 = e0 > 0.f ? e0 : LEAKY * e0;
        float e1 = ls_in[n1] + myld + etb[p1 >> 28]; e1 = e1 > 0.f ? e1 : LEAKY * e1;
        float e2 = ls_in[n2] + myld + etb[p2 >> 28]; e2 = e2 > 0.f ? e2 : LEAKY * e2;
        float e3 = ls_in[n3] + myld + etb[p3 >> 28]; e3 = e3 > 0.f ? e3 : LEAKY * e3;
        float w0 = __expf(e0 - mx), w1 = __expf(e1 - mx);
        float w2 = __expf(e2 - mx), w3 = __expf(e3 - mx);
        uint4 v0 = h4[(size_t)n0 * 8 + l];
        uint4 v1 = h4[(size_t)n1 * 8 + l];
        uint4 v2 = h4[(size_t)n2 * 8 + l];
        uint4 v3 = h4[(size_t)n3 * 8 + l];
        aw_ += (w0 + w1) + (w2 + w3);
        acc[0] += bflo(v0.x) * w0 + bflo(v1.x) * w1 + bflo(v2.x) * w2 + bflo(v3.x) * w3;
        acc[1] += bfhi(v0.x) * w0 + bfhi(v1.x) * w1 + bfhi(v2.x) * w2 + bfhi(v3.x) * w3;
        acc[2] += bflo(v0.y) * w0 + bflo(v1.y) * w1 + bflo(v2.y) * w2 + bflo(v3.y) * w3;
        acc[3] += bfhi(v0.y) * w0 + bfhi(v1.y) * w1 + bfhi(v2.y) * w2 + bfhi(v3.y) * w3;
        acc[4] += bflo(v0.z) * w0 + bflo(v1.z) * w1 + bflo(v2.z) * w2 + bflo(v3.z) * w3;
        acc[5] += bfhi(v0.z) * w0 + bfhi(v1.z) * w1 + bfhi(v2.z) * w2 + bfhi(v3.z) * w3;
        acc[6] += bflo(v0.w) * w0 + bflo(v1.w) * w1 + bflo(v2.w) * w2 + bflo(v3.w) * w3;
        acc[7] += bfhi(v0.w) * w0 + bfhi(v1.w) * w1 + bfhi(v2.w) * w2 + bfhi(v3.w) * w3;
    }
    for (; j < s1; j++) {
        unsigned p0 = pedge[j];
        unsigned n0 = p0 & 0x0FFFFFFFu;
        float e0 = ls_in[n0] + myld + etb[p0 >> 28]; e0 = e0 > 0.f ? e0 : LEAKY * e0;
        float w0 = __expf(e0 - mx);
        uint4 v0 = h4[(size_t)n0 * 8 + l];
        aw_ += w0;
        acc[0] += bflo(v0.x) * w0; acc[1] += bfhi(v0.x) * w0;
        acc[2] += bflo(v0.y) * w0; acc[3] += bfhi(v0.y) * w0;
        acc[4] += bflo(v0.z) * w0; acc[5] += bfhi(v0.z) * w0;
        acc[6] += bflo(v0.w) * w0; acc[7] += bfhi(v0.w) * w0;
    }
    float invd = 1.0f / (aw_ + 1e-16f);
    float4 o0, o1;
    o0.x = fmaxf(acc[0] * invd, 0.f); o0.y = fmaxf(acc[1] * invd, 0.f);
    o0.z = fmaxf(acc[2] * invd, 0.f); o0.w = fmaxf(acc[3] * invd, 0.f);
    o1.x = fmaxf(acc[4] * invd, 0.f); o1.y = fmaxf(acc[5] * invd, 0.f);
    o1.z = fmaxf(acc[6] * invd, 0.f); o1.w = fmaxf(acc[7] * invd, 0.f);
    *(float4*)&out[(size_t)n * 64 + l * 8] = o0;
    *(float4*)&out[(size_t)n * 64 + l * 8 + 4] = o1;
}

// ---------------- fused pool + critic MLP ----------------
__global__ __launch_bounds__(128) void poolmlp_k(const int* __restrict__ batch,
                                                 const float* __restrict__ act,
                                                 const float* __restrict__ W0,
                                                 const float* __restrict__ b0,
                                                 const float* __restrict__ W1,
                                                 const float* __restrict__ b1,
                                                 const float* __restrict__ fW,
                                                 const float* __restrict__ fb,
                                                 float* __restrict__ out, int N) {
    __shared__ float s[128];
    __shared__ float gv[64];
    __shared__ float t1[128];
    __shared__ float t2[128];
    __shared__ float part[2];
    int g = blockIdx.x;
    int t = threadIdx.x;
    int f = t & 63;
    int rc = t >> 6;   // 0..1
    int lo, hi;
    { int a = 0, b = N; while (a < b) { int m = (a + b) >> 1; if (batch[m] < g) a = m + 1; else b = m; } lo = a; }
    { int a = lo, b = N; while (a < b) { int m = (a + b) >> 1; if (batch[m] < g + 1) a = m + 1; else b = m; } hi = a; }
    float acc = 0.f;
    for (int n = lo + rc; n < hi; n += 2) acc += act[(size_t)n * 64 + f];
    s[t] = acc;
    __syncthreads();
    if (t < 64) gv[t] = s[t] + s[t + 64];
    __syncthreads();
    acc = b0[t];
    for (int k = 0; k < 64; k++) acc += gv[k] * W0[k * 128 + t];
    t1[t] = fmaxf(acc, 0.f);
    __syncthreads();
    acc = b1[t];
    for (int k = 0; k < 128; k++) acc += t1[k] * W1[k * 128 + t];
    t2[t] = fmaxf(acc, 0.f);
    __syncthreads();
    float v = t2[t] * fW[t];
    for (int o = 32; o > 0; o >>= 1) v += __shfl_xor(v, o, 64);
    if ((t & 63) == 0) part[t >> 6] = v;
    __syncthreads();
    if (t == 0) out[g] = part[0] + part[1] + fb[0];
}

extern "C" void kernel_launch(void* const* d_in, const int* in_sizes, int n_in,
                              void* d_out, int out_size, void* d_ws, size_t ws_size,
                              hipStream_t stream) {
    const float* x    = (const float*)d_in[0];
    const int*   src  = (const int*)d_in[1];
    const int*   dst  = (const int*)d_in[2];
    const int*   et   = (const int*)d_in[3];
    const int*   batch= (const int*)d_in[4];
    const float* W0   = (const float*)d_in[6];
    const float* W1   = (const float*)d_in[7];
    const float* W2   = (const float*)d_in[8];
    const float* a_src= (const float*)d_in[9];
    const float* a_dst= (const float*)d_in[10];
    const float* etb  = (const float*)d_in[11];
    const float* eW0  = (const float*)d_in[12];
    const float* eb0  = (const float*)d_in[13];
    const float* eW1  = (const float*)d_in[14];
    const float* eb1  = (const float*)d_in[15];
    const float* fW   = (const float*)d_in[16];
    const float* fb   = (const float*)d_in[17];
    float* out = (float*)d_out;

    const int H = in_sizes[9] / 3;       // 64
    const int F = in_sizes[6] / H;       // 128
    const int N = in_sizes[0] / F;       // 50000
    const int E = in_sizes[1];           // 800000
    const int T = in_sizes[11] / 3;      // 3
    const int G = out_size;              // 512

    unsigned short* hA = (unsigned short*)d_ws;                 // N*64 bf16
    unsigned short* hC = hA + (size_t)N * 64;                   // N*64 bf16
    float*    hB    = (float*)(hC + (size_t)N * 64);            // N*64 fp32
    float*    ls0   = hB + (size_t)N * 64;                      // N
    float*    ld0   = ls0 + N;                                  // N
    float*    ls1   = ld0 + N;                                  // N
    float*    ld1   = ls1 + N;                                  // N
    int*      deg   = (int*)(ld1 + N);                          // N
    int*      offs  = deg + N;                                  // N+1
    int*      rank  = offs + N + 1;                             // E
    unsigned* pedge = (unsigned*)(rank + E);                    // E
    int*      bsum  = (int*)(pedge + E);                        // NB

    const int NB = (N + SCAN_B - 1) / SCAN_B;
    const int NB64 = (N + 63) / 64;
    const int NB32 = (N + 31) / 32;

    zero_k<<<(N + 255) / 256, 256, 0, stream>>>(deg, N);
    rank_k<<<(E + 255) / 256, 256, 0, stream>>>(dst, deg, rank, E);
    scan1_k<<<NB, SCAN_B, 0, stream>>>(deg, offs, bsum, N);
    scan2_k<<<1, 64, 0, stream>>>(bsum, offs, NB, N);
    scan3_k<<<NB, SCAN_B, 0, stream>>>(offs, bsum, N);
    scatter_k<<<(E + 255) / 256, 256, 0, stream>>>(src, dst, et, offs, rank, pedge, E);

    // layer 0: x -> h0 (hA), logits0
    gemm_fused_k<128><<<NB64, 256, 0, stream>>>(x, W0, a_src + 0 * H, a_dst + 0 * H, hA, ls0, ld0, N);
    // layer 1: attn(h0) -> gemm W1 -> h1 (hC), logits1   (32 nodes/block)
    attn_gemm_k<<<NB32, 256, 0, stream>>>(offs, pedge, ls0, ld0, etb + 0 * T, hA,
                                          W1, a_src + 1 * H, a_dst + 1 * H, hC, ls1, ld1, N);
    // layer 2: attn(h1) -> gemm W2 -> h2 (hA), logits2
    attn_gemm_k<<<NB32, 256, 0, stream>>>(offs, pedge, ls1, ld1, etb + 1 * T, hC,
                                          W2, a_src + 2 * H, a_dst + 2 * H, hA, ls0, ld0, N);
    // final attn: attn(h2) -> hB (fp32)
    attn_final_k<<<NB32, 256, 0, stream>>>(offs, pedge, ls0, ld0, etb + 2 * T, hA, hB, N);

    // pool + MLP
    poolmlp_k<<<G, 128, 0, stream>>>(batch, hB, eW0, eb0, eW1, eb1, fW, fb, out, N);
}

// Round 13
// 193.027 us; speedup vs baseline: 1.1355x; 1.0144x over previous
//
#include <hip/hip_runtime.h>
#include <hip/hip_bf16.h>
#include <float.h>

#define LEAKY 0.2f
#define SCAN_B 512

__device__ __forceinline__ unsigned short f2bf_rne(float f) {
    unsigned u = __float_as_uint(f);
    unsigned r = (u + 0x7FFFu + ((u >> 16) & 1u)) >> 16;
    return (unsigned short)r;
}
__device__ __forceinline__ float bflo(unsigned u) { return __uint_as_float(u << 16); }
__device__ __forceinline__ float bfhi(unsigned u) { return __uint_as_float(u & 0xFFFF0000u); }

// ---------------- CSR build ----------------
__global__ void zero_k(int* __restrict__ p, int n) {
    int i = blockIdx.x * blockDim.x + threadIdx.x;
    if (i < n) p[i] = 0;
}

__global__ void rank_k(const int* __restrict__ dst, int* __restrict__ deg,
                       int* __restrict__ rank, int E) {
    int e = blockIdx.x * blockDim.x + threadIdx.x;
    if (e < E) rank[e] = atomicAdd(&deg[dst[e]], 1);
}

__global__ void scan1_k(const int* __restrict__ deg, int* __restrict__ offs,
                        int* __restrict__ bsum, int N) {
    __shared__ int s[SCAN_B];
    int i = blockIdx.x * SCAN_B + threadIdx.x;
    int v = (i < N) ? deg[i] : 0;
    s[threadIdx.x] = v;
    __syncthreads();
    for (int off = 1; off < SCAN_B; off <<= 1) {
        int t = (threadIdx.x >= off) ? s[threadIdx.x - off] : 0;
        __syncthreads();
        s[threadIdx.x] += t;
        __syncthreads();
    }
    if (i < N) offs[i] = s[threadIdx.x] - v;   // exclusive
    if (threadIdx.x == SCAN_B - 1) bsum[blockIdx.x] = s[threadIdx.x];
}

__global__ void scan2_k(int* __restrict__ bsum, int* __restrict__ offs, int NB, int N) {
    int lane = threadIdx.x;   // 64 threads
    int carry = 0;
    for (int base = 0; base < NB; base += 64) {
        int i = base + lane;
        int v = (i < NB) ? bsum[i] : 0;
        int s = v;
        for (int o = 1; o < 64; o <<= 1) {
            int t = __shfl_up(s, o, 64);
            if (lane >= o) s += t;
        }
        if (i < NB) bsum[i] = s - v + carry;
        carry += __shfl(s, 63, 64);
    }
    if (lane == 0) offs[N] = carry;
}

__global__ void scan3_k(int* __restrict__ offs, const int* __restrict__ bsum, int N) {
    int i = blockIdx.x * blockDim.x + threadIdx.x;
    if (i < N) offs[i] += bsum[i / SCAN_B];
}

__global__ void scatter_k(const int* __restrict__ src, const int* __restrict__ dst,
                          const int* __restrict__ et, const int* __restrict__ offs,
                          const int* __restrict__ rank, unsigned* __restrict__ pedge, int E) {
    int e = blockIdx.x * blockDim.x + threadIdx.x;
    if (e < E) {
        int j = offs[dst[e]] + rank[e];
        pedge[j] = ((unsigned)et[e] << 28) | (unsigned)src[e];
    }
}

// ---------------- layer-0 GEMM + logits ----------------
template <int FIN>
__global__ __launch_bounds__(256) void gemm_fused_k(const float* __restrict__ in,
                                                    const float* __restrict__ W,
                                                    const float* __restrict__ a_s,
                                                    const float* __restrict__ a_d,
                                                    unsigned short* __restrict__ h,
                                                    float* __restrict__ ls,
                                                    float* __restrict__ ld_, int N) {
    __shared__ float in_s[64][FIN + 4];
    __shared__ float Wl[FIN][64];

    const int rbase = blockIdx.x * 64;
    const int NV4 = FIN / 4;

    for (int t = threadIdx.x; t < FIN * 16; t += 256) {
        float4 v = *(const float4*)(W + (size_t)t * 4);
        *(float4*)((float*)Wl + (size_t)t * 4) = v;
    }
    for (int t = threadIdx.x; t < 64 * NV4; t += 256) {
        int r = t / NV4, k4 = t % NV4;
        int gr = rbase + r;
        if (gr >= N) gr = N - 1;
        float4 v = *(const float4*)(in + (size_t)gr * FIN + k4 * 4);
        *(float4*)&in_s[r][k4 * 4] = v;
    }
    __syncthreads();

    const int ty = threadIdx.x >> 4;
    const int tx = threadIdx.x & 15;

    float acc[4][4] = {};
#pragma unroll 4
    for (int k = 0; k < FIN; ++k) {
        float4 wv = *(const float4*)&Wl[k][tx * 4];
        float a0 = in_s[ty * 4 + 0][k];
        float a1 = in_s[ty * 4 + 1][k];
        float a2 = in_s[ty * 4 + 2][k];
        float a3 = in_s[ty * 4 + 3][k];
        acc[0][0] += a0 * wv.x; acc[0][1] += a0 * wv.y; acc[0][2] += a0 * wv.z; acc[0][3] += a0 * wv.w;
        acc[1][0] += a1 * wv.x; acc[1][1] += a1 * wv.y; acc[1][2] += a1 * wv.z; acc[1][3] += a1 * wv.w;
        acc[2][0] += a2 * wv.x; acc[2][1] += a2 * wv.y; acc[2][2] += a2 * wv.z; acc[2][3] += a2 * wv.w;
        acc[3][0] += a3 * wv.x; acc[3][1] += a3 * wv.y; acc[3][2] += a3 * wv.z; acc[3][3] += a3 * wv.w;
    }

    float4 asv = *(const float4*)(a_s + tx * 4);
    float4 adv = *(const float4*)(a_d + tx * 4);
#pragma unroll
    for (int i = 0; i < 4; ++i) {
        int row = rbase + ty * 4 + i;
        float lsv = acc[i][0] * asv.x + acc[i][1] * asv.y + acc[i][2] * asv.z + acc[i][3] * asv.w;
        float ldv = acc[i][0] * adv.x + acc[i][1] * adv.y + acc[i][2] * adv.z + acc[i][3] * adv.w;
        for (int o = 1; o < 16; o <<= 1) {
            lsv += __shfl_xor(lsv, o, 64);
            ldv += __shfl_xor(ldv, o, 64);
        }
        if (row < N) {
            ushort4 hv;
            hv.x = f2bf_rne(acc[i][0]);
            hv.y = f2bf_rne(acc[i][1]);
            hv.z = f2bf_rne(acc[i][2]);
            hv.w = f2bf_rne(acc[i][3]);
            ((ushort4*)h)[(size_t)row * 16 + tx] = hv;
            if (tx == 0) { ls[row] = lsv; ld_[row] = ldv; }
        }
    }
}

// Shared attn body: 16-lane group per node, 2-way edge split (lanes 0-7 vs 8-15).
// Each lane owns a 16B slice (l = lane&7); sub = lane>>3 picks the edge half.
// Returns combined acc[8], aw_ in ALL 16 lanes (post shfl_xor 8).
#define ATTN_BODY(S0, S1)                                                            \
    {                                                                                \
        int m = (S1) - (S0);                                                         \
        int half = m >> 1;                                                           \
        int js = sub ? (S0) + half : (S0);                                           \
        int je = sub ? (S1) : (S0) + half;                                           \
        /* pass 1: 16-lane parallel max */                                           \
        float mx = -FLT_MAX;                                                         \
        for (int j = (S0) + l16; j < (S1); j += 16) {                                \
            unsigned pp = pedge[j];                                                  \
            float ev = ls_in[pp & 0x0FFFFFFFu] + myld + etb[pp >> 28];               \
            ev = ev > 0.f ? ev : LEAKY * ev;                                         \
            mx = fmaxf(mx, ev);                                                      \
        }                                                                            \
        _Pragma("unroll")                                                            \
        for (int o = 1; o < 16; o <<= 1) mx = fmaxf(mx, __shfl_xor(mx, o, 64));      \
        /* pass 2: each sub-half serial 4-unroll */                                  \
        int j = js;                                                                  \
        for (; j + 3 < je; j += 4) {                                                 \
            unsigned p0 = pedge[j], p1 = pedge[j + 1], p2 = pedge[j + 2], p3 = pedge[j + 3]; \
            unsigned n0 = p0 & 0x0FFFFFFFu, n1 = p1 & 0x0FFFFFFFu;                   \
            unsigned n2 = p2 & 0x0FFFFFFFu, n3 = p3 & 0x0FFFFFFFu;                   \
            float e0 = ls_in[n0] + myld + etb[p0 >> 28]; e0 = e0 > 0.f ? e0 : LEAKY * e0; \
            float e1 = ls_in[n1] + myld + etb[p1 >> 28]; e1 = e1 > 0.f ? e1 : LEAKY * e1; \
            float e2 = ls_in[n2] + myld + etb[p2 >> 28]; e2 = e2 > 0.f ? e2 : LEAKY * e2; \
            float e3 = ls_in[n3] + myld + etb[p3 >> 28]; e3 = e3 > 0.f ? e3 : LEAKY * e3; \
            float w0 = __expf(e0 - mx), w1 = __expf(e1 - mx);                        \
            float w2 = __expf(e2 - mx), w3 = __expf(e3 - mx);                        \
            uint4 v0 = h4[(size_t)n0 * 8 + l];                                       \
            uint4 v1 = h4[(size_t)n1 * 8 + l];                                       \
            uint4 v2 = h4[(size_t)n2 * 8 + l];                                       \
            uint4 v3 = h4[(size_t)n3 * 8 + l];                                       \
            aw_ += (w0 + w1) + (w2 + w3);                                            \
            acc[0] += bflo(v0.x) * w0 + bflo(v1.x) * w1 + bflo(v2.x) * w2 + bflo(v3.x) * w3; \
            acc[1] += bfhi(v0.x) * w0 + bfhi(v1.x) * w1 + bfhi(v2.x) * w2 + bfhi(v3.x) * w3; \
            acc[2] += bflo(v0.y) * w0 + bflo(v1.y) * w1 + bflo(v2.y) * w2 + bflo(v3.y) * w3; \
            acc[3] += bfhi(v0.y) * w0 + bfhi(v1.y) * w1 + bfhi(v2.y) * w2 + bfhi(v3.y) * w3; \
            acc[4] += bflo(v0.z) * w0 + bflo(v1.z) * w1 + bflo(v2.z) * w2 + bflo(v3.z) * w3; \
            acc[5] += bfhi(v0.z) * w0 + bfhi(v1.z) * w1 + bfhi(v2.z) * w2 + bfhi(v3.z) * w3; \
            acc[6] += bflo(v0.w) * w0 + bflo(v1.w) * w1 + bflo(v2.w) * w2 + bflo(v3.w) * w3; \
            acc[7] += bfhi(v0.w) * w0 + bfhi(v1.w) * w1 + bfhi(v2.w) * w2 + bfhi(v3.w) * w3; \
        }                                                                            \
        for (; j < je; j++) {                                                        \
            unsigned p0 = pedge[j];                                                  \
            unsigned n0 = p0 & 0x0FFFFFFFu;                                          \
            float e0 = ls_in[n0] + myld + etb[p0 >> 28]; e0 = e0 > 0.f ? e0 : LEAKY * e0; \
            float w0 = __expf(e0 - mx);                                              \
            uint4 v0 = h4[(size_t)n0 * 8 + l];                                       \
            aw_ += w0;                                                               \
            acc[0] += bflo(v0.x) * w0; acc[1] += bfhi(v0.x) * w0;                    \
            acc[2] += bflo(v0.y) * w0; acc[3] += bfhi(v0.y) * w0;                    \
            acc[4] += bflo(v0.z) * w0; acc[5] += bfhi(v0.z) * w0;                    \
            acc[6] += bflo(v0.w) * w0; acc[7] += bfhi(v0.w) * w0;                    \
        }                                                                            \
        /* combine the two halves (lanes l and l+8) */                               \
        aw_ += __shfl_xor(aw_, 8, 64);                                               \
        _Pragma("unroll")                                                            \
        for (int q = 0; q < 8; ++q) acc[q] += __shfl_xor(acc[q], 8, 64);             \
    }

// ---------------- fused attn (2-edge-split) + GEMM, 16 nodes/block ----------------
__global__ __launch_bounds__(256) void attn_gemm_k(const int* __restrict__ offs,
                                                   const unsigned* __restrict__ pedge,
                                                   const float* __restrict__ ls_in,
                                                   const float* __restrict__ ld_in,
                                                   const float* __restrict__ etb,
                                                   const unsigned short* __restrict__ h_in,
                                                   const float* __restrict__ W,
                                                   const float* __restrict__ a_s,
                                                   const float* __restrict__ a_d,
                                                   unsigned short* __restrict__ h_out,
                                                   float* __restrict__ ls_out,
                                                   float* __restrict__ ld_out, int N) {
    __shared__ float Wl[64][64];
    __shared__ float act[16][68];

    const int rbase = blockIdx.x * 16;

    for (int t = threadIdx.x; t < 64 * 16; t += 256)
        *(float4*)((float*)Wl + (size_t)t * 4) = *(const float4*)(W + (size_t)t * 4);

    const int grp = threadIdx.x >> 4;   // 0..15 -> node
    const int l16 = threadIdx.x & 15;
    const int sub = l16 >> 3;           // 0/1 -> edge half
    const int l = l16 & 7;              // 16B slice
    const uint4* h4 = (const uint4*)h_in;

    {
        int n = rbase + grp;
        float acc[8] = {};
        float aw_ = 0.f;
        if (n < N) {
            int s0 = offs[n], s1 = offs[n + 1];
            float myld = ld_in[n];
            ATTN_BODY(s0, s1)
        }
        float invd = 1.0f / (aw_ + 1e-16f);
        float4 o0, o1;
        o0.x = fmaxf(acc[0] * invd, 0.f); o0.y = fmaxf(acc[1] * invd, 0.f);
        o0.z = fmaxf(acc[2] * invd, 0.f); o0.w = fmaxf(acc[3] * invd, 0.f);
        o1.x = fmaxf(acc[4] * invd, 0.f); o1.y = fmaxf(acc[5] * invd, 0.f);
        o1.z = fmaxf(acc[6] * invd, 0.f); o1.w = fmaxf(acc[7] * invd, 0.f);
        if (n >= N) { o0 = make_float4(0, 0, 0, 0); o1 = o0; }
        if (sub == 0) {
            *(float4*)&act[grp][l * 8] = o0;
            *(float4*)&act[grp][l * 8 + 4] = o1;
        }
    }
    __syncthreads();

    // ---- gemm phase: 16 rows x 64 cols; each thread 1 row x 4 cols ----
    const int ty = threadIdx.x >> 4;
    const int tx = threadIdx.x & 15;

    float acc[4] = {};
#pragma unroll 4
    for (int k = 0; k < 64; ++k) {
        float4 wv = *(const float4*)&Wl[k][tx * 4];
        float a0 = act[ty][k];
        acc[0] += a0 * wv.x; acc[1] += a0 * wv.y; acc[2] += a0 * wv.z; acc[3] += a0 * wv.w;
    }

    float4 asv = *(const float4*)(a_s + tx * 4);
    float4 adv = *(const float4*)(a_d + tx * 4);
    {
        int row = rbase + ty;
        float lsv = acc[0] * asv.x + acc[1] * asv.y + acc[2] * asv.z + acc[3] * asv.w;
        float ldv = acc[0] * adv.x + acc[1] * adv.y + acc[2] * adv.z + acc[3] * adv.w;
        for (int o = 1; o < 16; o <<= 1) {
            lsv += __shfl_xor(lsv, o, 64);
            ldv += __shfl_xor(ldv, o, 64);
        }
        if (row < N) {
            ushort4 hv;
            hv.x = f2bf_rne(acc[0]);
            hv.y = f2bf_rne(acc[1]);
            hv.z = f2bf_rne(acc[2]);
            hv.w = f2bf_rne(acc[3]);
            ((ushort4*)h_out)[(size_t)row * 16 + tx] = hv;
            if (tx == 0) { ls_out[row] = lsv; ld_out[row] = ldv; }
        }
    }
}

// ---------------- final attn (2-edge-split, 16 nodes/block, fp32 output) ----------------
__global__ __launch_bounds__(256) void attn_final_k(const int* __restrict__ offs,
                                                    const unsigned* __restrict__ pedge,
                                                    const float* __restrict__ ls_in,
                                                    const float* __restrict__ ld_in,
                                                    const float* __restrict__ etb,
                                                    const unsigned short* __restrict__ h_in,
                                                    float* __restrict__ out, int N) {
    const int grp = threadIdx.x >> 4;
    const int l16 = threadIdx.x & 15;
    const int sub = l16 >> 3;
    const int l = l16 & 7;
    int n = blockIdx.x * 16 + grp;
    if (n >= N) return;
    int s0 = offs[n], s1 = offs[n + 1];
    float myld = ld_in[n];
    const uint4* h4 = (const uint4*)h_in;

    float acc[8] = {};
    float aw_ = 0.f;
    ATTN_BODY(s0, s1)

    if (sub == 0) {
        float invd = 1.0f / (aw_ + 1e-16f);
        float4 o0, o1;
        o0.x = fmaxf(acc[0] * invd, 0.f); o0.y = fmaxf(acc[1] * invd, 0.f);
        o0.z = fmaxf(acc[2] * invd, 0.f); o0.w = fmaxf(acc[3] * invd, 0.f);
        o1.x = fmaxf(acc[4] * invd, 0.f); o1.y = fmaxf(acc[5] * invd, 0.f);
        o1.z = fmaxf(acc[6] * invd, 0.f); o1.w = fmaxf(acc[7] * invd, 0.f);
        *(float4*)&out[(size_t)n * 64 + l * 8] = o0;
        *(float4*)&out[(size_t)n * 64 + l * 8 + 4] = o1;
    }
}

// ---------------- fused pool + critic MLP ----------------
__global__ __launch_bounds__(128) void poolmlp_k(const int* __restrict__ batch,
                                                 const float* __restrict__ act,
                                                 const float* __restrict__ W0,
                                                 const float* __restrict__ b0,
                                                 const float* __restrict__ W1,
                                                 const float* __restrict__ b1,
                                                 const float* __restrict__ fW,
                                                 const float* __restrict__ fb,
                                                 float* __restrict__ out, int N) {
    __shared__ float s[128];
    __shared__ float gv[64];
    __shared__ float t1[128];
    __shared__ float t2[128];
    __shared__ float part[2];
    int g = blockIdx.x;
    int t = threadIdx.x;
    int f = t & 63;
    int rc = t >> 6;   // 0..1
    int lo, hi;
    { int a = 0, b = N; while (a < b) { int m = (a + b) >> 1; if (batch[m] < g) a = m + 1; else b = m; } lo = a; }
    { int a = lo, b = N; while (a < b) { int m = (a + b) >> 1; if (batch[m] < g + 1) a = m + 1; else b = m; } hi = a; }
    float acc = 0.f;
    for (int n = lo + rc; n < hi; n += 2) acc += act[(size_t)n * 64 + f];
    s[t] = acc;
    __syncthreads();
    if (t < 64) gv[t] = s[t] + s[t + 64];
    __syncthreads();
    acc = b0[t];
    for (int k = 0; k < 64; k++) acc += gv[k] * W0[k * 128 + t];
    t1[t] = fmaxf(acc, 0.f);
    __syncthreads();
    acc = b1[t];
    for (int k = 0; k < 128; k++) acc += t1[k] * W1[k * 128 + t];
    t2[t] = fmaxf(acc, 0.f);
    __syncthreads();
    float v = t2[t] * fW[t];
    for (int o = 32; o > 0; o >>= 1) v += __shfl_xor(v, o, 64);
    if ((t & 63) == 0) part[t >> 6] = v;
    __syncthreads();
    if (t == 0) out[g] = part[0] + part[1] + fb[0];
}

extern "C" void kernel_launch(void* const* d_in, const int* in_sizes, int n_in,
                              void* d_out, int out_size, void* d_ws, size_t ws_size,
                              hipStream_t stream) {
    const float* x    = (const float*)d_in[0];
    const int*   src  = (const int*)d_in[1];
    const int*   dst  = (const int*)d_in[2];
    const int*   et   = (const int*)d_in[3];
    const int*   batch= (const int*)d_in[4];
    const float* W0   = (const float*)d_in[6];
    const float* W1   = (const float*)d_in[7];
    const float* W2   = (const float*)d_in[8];
    const float* a_src= (const float*)d_in[9];
    const float* a_dst= (const float*)d_in[10];
    const float* etb  = (const float*)d_in[11];
    const float* eW0  = (const float*)d_in[12];
    const float* eb0  = (const float*)d_in[13];
    const float* eW1  = (const float*)d_in[14];
    const float* eb1  = (const float*)d_in[15];
    const float* fW   = (const float*)d_in[16];
    const float* fb   = (const float*)d_in[17];
    float* out = (float*)d_out;

    const int H = in_sizes[9] / 3;       // 64
    const int F = in_sizes[6] / H;       // 128
    const int N = in_sizes[0] / F;       // 50000
    const int E = in_sizes[1];           // 800000
    const int T = in_sizes[11] / 3;      // 3
    const int G = out_size;              // 512

    unsigned short* hA = (unsigned short*)d_ws;                 // N*64 bf16
    unsigned short* hC = hA + (size_t)N * 64;                   // N*64 bf16
    float*    hB    = (float*)(hC + (size_t)N * 64);            // N*64 fp32
    float*    ls0   = hB + (size_t)N * 64;                      // N
    float*    ld0   = ls0 + N;                                  // N
    float*    ls1   = ld0 + N;                                  // N
    float*    ld1   = ls1 + N;                                  // N
    int*      deg   = (int*)(ld1 + N);                          // N
    int*      offs  = deg + N;                                  // N+1
    int*      rank  = offs + N + 1;                             // E
    unsigned* pedge = (unsigned*)(rank + E);                    // E
    int*      bsum  = (int*)(pedge + E);                        // NB

    const int NB = (N + SCAN_B - 1) / SCAN_B;
    const int NB64 = (N + 63) / 64;
    const int NB16 = (N + 15) / 16;

    zero_k<<<(N + 255) / 256, 256, 0, stream>>>(deg, N);
    rank_k<<<(E + 255) / 256, 256, 0, stream>>>(dst, deg, rank, E);
    scan1_k<<<NB, SCAN_B, 0, stream>>>(deg, offs, bsum, N);
    scan2_k<<<1, 64, 0, stream>>>(bsum, offs, NB, N);
    scan3_k<<<NB, SCAN_B, 0, stream>>>(offs, bsum, N);
    scatter_k<<<(E + 255) / 256, 256, 0, stream>>>(src, dst, et, offs, rank, pedge, E);

    // layer 0: x -> h0 (hA), logits0
    gemm_fused_k<128><<<NB64, 256, 0, stream>>>(x, W0, a_src + 0 * H, a_dst + 0 * H, hA, ls0, ld0, N);
    // layer 1: attn(h0) -> gemm W1 -> h1 (hC), logits1   (16 nodes/block)
    attn_gemm_k<<<NB16, 256, 0, stream>>>(offs, pedge, ls0, ld0, etb + 0 * T, hA,
                                          W1, a_src + 1 * H, a_dst + 1 * H, hC, ls1, ld1, N);
    // layer 2: attn(h1) -> gemm W2 -> h2 (hA), logits2
    attn_gemm_k<<<NB16, 256, 0, stream>>>(offs, pedge, ls1, ld1, etb + 1 * T, hC,
                                          W2, a_src + 2 * H, a_dst + 2 * H, hA, ls0, ld0, N);
    // final attn: attn(h2) -> hB (fp32)
    attn_final_k<<<NB16, 256, 0, stream>>>(offs, pedge, ls0, ld0, etb + 2 * T, hA, hB, N);

    // pool + MLP
    poolmlp_k<<<G, 128, 0, stream>>>(batch, hB, eW0, eb0, eW1, eb1, fW, fb, out, N);
}